// Round 5
// baseline (221.682 us; speedup 1.0000x reference)
//
#include <hip/hip_runtime.h>
#include <math.h>

#define SIG_THRESHOLD 0.01f
#define PHASE_INT_THR 0.01f
#define TWO_PI_F 6.283185307179586f

// ---------------- fast atan2 ----------------
// Range-reduce to t = min/max in [0,1], degree-11 odd minimax for atan(t),
// then quadrant fixup + copysign. Verified absmax 0.0 in R3/R4 bench.
__device__ __forceinline__ float fast_atan2f(float y, float x) {
    float ax = fabsf(x), ay = fabsf(y);
    float mx = fmaxf(ax, ay), mn = fminf(ax, ay);
    float t = mn * __builtin_amdgcn_rcpf(mx);
    t = (mx == 0.0f) ? 0.0f : t;          // atan2(0,0) -> 0
    float s = t * t;
    float p =        -0.01172120f;
    p = fmaf(s, p,    0.05265332f);
    p = fmaf(s, p,   -0.11643287f);
    p = fmaf(s, p,    0.19354346f);
    p = fmaf(s, p,   -0.33262347f);
    p = fmaf(s, p,    0.99997726f);
    float r = p * t;                       // atan(mn/mx) in [0, pi/4]
    r = (ay > ax) ? (1.57079632679f - r) : r;
    r = (x < 0.0f) ? (3.14159265359f - r) : r;
    return copysignf(r, y);
}

// ---------------- block reduction helpers ----------------

__device__ __forceinline__ float waveReduceSum(float v) {
#pragma unroll
    for (int o = 32; o > 0; o >>= 1) v += __shfl_down(v, o, 64);
    return v;
}
__device__ __forceinline__ int waveReduceMin(int v) {
#pragma unroll
    for (int o = 32; o > 0; o >>= 1) v = min(v, __shfl_down(v, o, 64));
    return v;
}
__device__ __forceinline__ int waveReduceMax(int v) {
#pragma unroll
    for (int o = 32; o > 0; o >>= 1) v = max(v, __shfl_down(v, o, 64));
    return v;
}

__device__ __forceinline__ float blockReduceSum(float v, float* lds) {
    __syncthreads();
    v = waveReduceSum(v);
    int lane = threadIdx.x & 63, wave = threadIdx.x >> 6;
    if (lane == 0) lds[wave] = v;
    __syncthreads();
    int nw = (blockDim.x + 63) >> 6;
    float r = (threadIdx.x < nw) ? lds[threadIdx.x] : 0.0f;
    if (threadIdx.x < 64) r = waveReduceSum(r);
    if (threadIdx.x == 0) lds[0] = r;
    __syncthreads();
    return lds[0];
}
__device__ __forceinline__ int blockReduceMin(int v, int* lds) {
    __syncthreads();
    v = waveReduceMin(v);
    int lane = threadIdx.x & 63, wave = threadIdx.x >> 6;
    if (lane == 0) lds[wave] = v;
    __syncthreads();
    int nw = (blockDim.x + 63) >> 6;
    int r = (threadIdx.x < nw) ? lds[threadIdx.x] : 0x7fffffff;
    if (threadIdx.x < 64) r = waveReduceMin(r);
    if (threadIdx.x == 0) lds[0] = r;
    __syncthreads();
    return lds[0];
}
__device__ __forceinline__ int blockReduceMax(int v, int* lds) {
    __syncthreads();
    v = waveReduceMax(v);
    int lane = threadIdx.x & 63, wave = threadIdx.x >> 6;
    if (lane == 0) lds[wave] = v;
    __syncthreads();
    int nw = (blockDim.x + 63) >> 6;
    int r = (threadIdx.x < nw) ? lds[threadIdx.x] : (int)0x80000000;
    if (threadIdx.x < 64) r = waveReduceMax(r);
    if (threadIdx.x == 0) lds[0] = r;
    __syncthreads();
    return lds[0];
}

#define COARSE_SENT (1 << 29)

// ---------------- per-float4 body ----------------
// Single-atan2 phase diff: dph = w + 2pi*sigma, w = atan2(cross, dot).
// sigma=+1 iff (phi_p>0 & phi_l<=0 & w<0); sigma=-1 iff (phi_p<=0 & phi_l>0 & w>0).
__device__ __forceinline__ void process4(float4 lrv, float4 liv, float4 prv, float4 piv,
                                         int v,
                                         float& sum_r, float& sum_i, float& sum_int, float& sum_ph,
                                         int& cfr4, int& clr4, int& cfi4, int& cli4) {
#pragma unroll
    for (int k = 0; k < 4; ++k) {
        float lrk = (&lrv.x)[k], lik = (&liv.x)[k];
        float prk = (&prv.x)[k], pik = (&piv.x)[k];

        float dr = prk - lrk;  sum_r = fmaf(dr, dr, sum_r);
        float di = pik - lik;  sum_i = fmaf(di, di, sum_i);

        float lint = fmaf(lrk, lrk, lik * lik);
        float pint = fmaf(prk, prk, pik * pik);
        float dint = pint - lint;  sum_int = fmaf(dint, dint, sum_int);

        float cross = fmaf(pik, lrk, -(prk * lik));   // pi*lr - pr*li
        float dotv  = fmaf(prk, lrk,   pik * lik);    // pr*lr + pi*li
        float w = fast_atan2f(cross, dotv);
        bool php = pik > 0.0f;                        // phi_pred > 0
        bool phl = lik > 0.0f;                        // phi_label > 0
        float sigma = (php && !phl && w < 0.0f) ?  1.0f
                    : ((!php && phl && w > 0.0f) ? -1.0f : 0.0f);
        float dph = fmaf(sigma, TWO_PI_F, w);
        sum_ph += (lint >= PHASE_INT_THR) ? dph * dph : 0.0f;
    }
    // coarse significance per float4 (abs folds into v_max_f32 modifiers)
    float amr = fmaxf(fmaxf(fabsf(lrv.x), fabsf(lrv.y)), fmaxf(fabsf(lrv.z), fabsf(lrv.w)));
    float ami = fmaxf(fmaxf(fabsf(liv.x), fabsf(liv.y)), fmaxf(fabsf(liv.z), fabsf(liv.w)));
    bool sr = amr > SIG_THRESHOLD;
    bool si = ami > SIG_THRESHOLD;
    cfr4 = min(cfr4, sr ? v : COARSE_SENT);
    clr4 = sr ? v : clr4;                 // v monotone increasing per thread
    cfi4 = min(cfi4, si ? v : COARSE_SENT);
    cli4 = si ? v : cli4;
}

// ---------------- epilogue shared by both kernels ----------------
__device__ __forceinline__ void row_epilogue(const float* __restrict__ P,
                                             const float* __restrict__ L,
                                             float* __restrict__ row_out, int row, int n,
                                             float sum_r, float sum_i, float sum_int, float sum_ph,
                                             int cfr4, int clr4, int cfi4, int cli4,
                                             float* s_f, int* s_i, int* s_b) {
    const int tid = threadIdx.x;
    const int nt  = blockDim.x;

    float tot_r   = blockReduceSum(sum_r, s_f);
    float tot_i   = blockReduceSum(sum_i, s_f);
    float tot_int = blockReduceSum(sum_int, s_f);
    float tot_ph  = blockReduceSum(sum_ph, s_f);

    int fr4 = blockReduceMin(cfr4, s_i);
    int lr4 = blockReduceMax(clr4, s_i);
    int fi4 = blockReduceMin(cfi4, s_i);
    int li4 = blockReduceMax(cli4, s_i);

    // refine coarse (float4-granularity) bounds to exact element bounds
    if (tid < 4) s_b[tid] = (tid & 1) ? -1 : n;
    __syncthreads();
    if (tid < 16) {
        int which = tid >> 2;                     // 0:fr 1:lr 2:fi 3:li
        int k = tid & 3;
        const float* base = (which >= 2) ? (L + n) : L;
        int v4 = (which == 0) ? fr4 : (which == 1) ? lr4 : (which == 2) ? fi4 : li4;
        bool valid = (which & 1) ? (v4 >= 0) : (v4 < COARSE_SENT);
        if (valid) {
            int idx = v4 * 4 + k;
            if (fabsf(base[idx]) > SIG_THRESHOLD) {
                if (which & 1) atomicMax(&s_b[which], idx);
                else           atomicMin(&s_b[which], idx);
            }
        }
    }
    __syncthreads();
    int fr = s_b[0], lr = s_b[1], fi = s_b[2], li = s_b[3];
    if (fr == n) { fr = 0; lr = n - 1; }   // no significant element: scale 1 everywhere
    if (fi == n) { fi = 0; li = n - 1; }

    // extra 1x contribution for the two outside spans (usually ~empty)
    float o_r = 0.f, o_i = 0.f;
    for (int i = tid; i < fr; i += nt)          { float d = P[i] - L[i];         o_r += d * d; }
    for (int i = lr + 1 + tid; i < n; i += nt)  { float d = P[i] - L[i];         o_r += d * d; }
    for (int i = tid; i < fi; i += nt)          { float d = P[n + i] - L[n + i]; o_i += d * d; }
    for (int i = li + 1 + tid; i < n; i += nt)  { float d = P[n + i] - L[n + i]; o_i += d * d; }

    float tot_or = blockReduceSum(o_r, s_f);
    float tot_oi = blockReduceSum(o_i, s_f);

    if (tid == 0) {
        float wr = tot_r + tot_or;
        float wi = tot_i + tot_oi;
        row_out[row] = (wr + wi + 10.0f * tot_int + 5.0f * tot_ph) / (float)n;
    }
}

// ---------------- specialized pipelined kernel (n = NT*ITERS*8) ----------------
template<int NT, int ITERS>
__global__ void __launch_bounds__(NT, 4)
prl_row_fast(const float* __restrict__ pred, const float* __restrict__ label,
             float* __restrict__ row_out, int n, int two_n) {
    __shared__ float s_f[16];
    __shared__ int s_i[16];
    __shared__ int s_b[4];

    const int row = blockIdx.x;
    const float* __restrict__ P = pred  + (size_t)row * two_n;
    const float* __restrict__ L = label + (size_t)row * two_n;
    const int tid = threadIdx.x;

    const float4* __restrict__ Lr4 = reinterpret_cast<const float4*>(L);
    const float4* __restrict__ Li4 = reinterpret_cast<const float4*>(L + n);
    const float4* __restrict__ Pr4 = reinterpret_cast<const float4*>(P);
    const float4* __restrict__ Pi4 = reinterpret_cast<const float4*>(P + n);

    float sum_r = 0.f, sum_i = 0.f, sum_int = 0.f, sum_ph = 0.f;
    int cfr4 = COARSE_SENT, clr4 = -1, cfi4 = COARSE_SENT, cli4 = -1;

    // register double-buffer: prologue loads iteration 0
    int v = tid;
    float4 a0 = Lr4[v],      b0 = Li4[v],      c0 = Pr4[v],      d0 = Pi4[v];
    float4 a1 = Lr4[v + NT], b1 = Li4[v + NT], c1 = Pr4[v + NT], d1 = Pi4[v + NT];

#pragma unroll
    for (int it = 0; it < ITERS; ++it) {
        float4 na0 = a0, nb0 = b0, nc0 = c0, nd0 = d0;
        float4 na1 = a1, nb1 = b1, nc1 = c1, nd1 = d1;
        if (it + 1 < ITERS) {                        // compile-time after unroll
            const int vn  = v + 2 * NT;
            const int vn1 = vn + NT;
            na0 = Lr4[vn];  nb0 = Li4[vn];  nc0 = Pr4[vn];  nd0 = Pi4[vn];
            na1 = Lr4[vn1]; nb1 = Li4[vn1]; nc1 = Pr4[vn1]; nd1 = Pi4[vn1];
        }
        __builtin_amdgcn_sched_barrier(0);           // pin prefetch loads above compute
        process4(a0, b0, c0, d0, v,      sum_r, sum_i, sum_int, sum_ph, cfr4, clr4, cfi4, cli4);
        process4(a1, b1, c1, d1, v + NT, sum_r, sum_i, sum_int, sum_ph, cfr4, clr4, cfi4, cli4);
        a0 = na0; b0 = nb0; c0 = nc0; d0 = nd0;
        a1 = na1; b1 = nb1; c1 = nc1; d1 = nd1;
        v += 2 * NT;
    }

    row_epilogue(P, L, row_out, row, n, sum_r, sum_i, sum_int, sum_ph,
                 cfr4, clr4, cfi4, cli4, s_f, s_i, s_b);
}

// ---------------- generic fallback ----------------
__global__ void __launch_bounds__(512)
prl_row_generic(const float* __restrict__ pred, const float* __restrict__ label,
                float* __restrict__ row_out, int n, int two_n) {
    __shared__ float s_f[16];
    __shared__ int s_i[16];
    __shared__ int s_b[4];

    const int row = blockIdx.x;
    const float* __restrict__ P = pred  + (size_t)row * two_n;
    const float* __restrict__ L = label + (size_t)row * two_n;
    const int tid = threadIdx.x;
    const int nt  = blockDim.x;

    const float4* __restrict__ Lr4 = reinterpret_cast<const float4*>(L);
    const float4* __restrict__ Li4 = reinterpret_cast<const float4*>(L + n);
    const float4* __restrict__ Pr4 = reinterpret_cast<const float4*>(P);
    const float4* __restrict__ Pi4 = reinterpret_cast<const float4*>(P + n);

    float sum_r = 0.f, sum_i = 0.f, sum_int = 0.f, sum_ph = 0.f;
    int cfr4 = COARSE_SENT, clr4 = -1, cfi4 = COARSE_SENT, cli4 = -1;

    const int nvec = n / 4;
    for (int v = tid; v < nvec; v += nt) {
        float4 a = Lr4[v], b = Li4[v], c = Pr4[v], d = Pi4[v];
        process4(a, b, c, d, v, sum_r, sum_i, sum_int, sum_ph, cfr4, clr4, cfi4, cli4);
    }

    row_epilogue(P, L, row_out, row, n, sum_r, sum_i, sum_int, sum_ph,
                 cfr4, clr4, cfi4, cli4, s_f, s_i, s_b);
}

// ---------------- finalize: mean over rows ----------------
__global__ void __launch_bounds__(1024)
prl_finalize_kernel(const float* __restrict__ rows, float* __restrict__ out, int B) {
    __shared__ float s_f[16];
    float v = 0.f;
    for (int i = threadIdx.x; i < B; i += blockDim.x) v += rows[i];
    float t = blockReduceSum(v, s_f);
    if (threadIdx.x == 0) out[0] = t / (float)B;
}

extern "C" void kernel_launch(void* const* d_in, const int* in_sizes, int n_in,
                              void* d_out, int out_size, void* d_ws, size_t ws_size,
                              hipStream_t stream) {
    const float* pred  = (const float*)d_in[0];
    const float* label = (const float*)d_in[1];
    // spectrogram (d_in[2]) is unused by the reference.

    const int B     = in_sizes[2] / (128 * 128);   // 1024
    const int two_n = in_sizes[0] / B;             // 65536
    const int n     = two_n / 2;                   // 32768

    float* row_out = (float*)d_ws;                 // B floats of scratch
    float* out     = (float*)d_out;

    constexpr int NT = 512, ITERS = 8;
    if (n == NT * ITERS * 8) {                     // 32768: specialized pipeline
        prl_row_fast<NT, ITERS><<<B, NT, 0, stream>>>(pred, label, row_out, n, two_n);
    } else {
        prl_row_generic<<<B, 512, 0, stream>>>(pred, label, row_out, n, two_n);
    }
    prl_finalize_kernel<<<1, 1024, 0, stream>>>(row_out, out, B);
}

// Round 6
// 103.341 us; speedup vs baseline: 2.1452x; 2.1452x over previous
//
#include <hip/hip_runtime.h>
#include <math.h>

#define SIG_THRESHOLD 0.01f
#define PHASE_INT_THR 0.01f
#define TWO_PI_F 6.283185307179586f

// ---------------- fast atan2 ----------------
// Range-reduce to t = min/max in [0,1], degree-11 odd minimax for atan(t),
// then quadrant fixup + copysign. Verified absmax 0.0 (R3-R5).
__device__ __forceinline__ float fast_atan2f(float y, float x) {
    float ax = fabsf(x), ay = fabsf(y);
    float mx = fmaxf(ax, ay), mn = fminf(ax, ay);
    float t = mn * __builtin_amdgcn_rcpf(mx);
    t = (mx == 0.0f) ? 0.0f : t;          // atan2(0,0) -> 0
    float s = t * t;
    float p =        -0.01172120f;
    p = fmaf(s, p,    0.05265332f);
    p = fmaf(s, p,   -0.11643287f);
    p = fmaf(s, p,    0.19354346f);
    p = fmaf(s, p,   -0.33262347f);
    p = fmaf(s, p,    0.99997726f);
    float r = p * t;                       // atan(mn/mx) in [0, pi/4]
    r = (ay > ax) ? (1.57079632679f - r) : r;
    r = (x < 0.0f) ? (3.14159265359f - r) : r;
    return copysignf(r, y);
}

// ---------------- fused block reductions ----------------

__device__ __forceinline__ float4 waveReduceSum4(float4 v) {
#pragma unroll
    for (int o = 32; o > 0; o >>= 1) {
        v.x += __shfl_down(v.x, o, 64);
        v.y += __shfl_down(v.y, o, 64);
        v.z += __shfl_down(v.z, o, 64);
        v.w += __shfl_down(v.w, o, 64);
    }
    return v;
}

// x,z reduced with min; y,w reduced with max
__device__ __forceinline__ int4 waveReduceBounds(int4 v) {
#pragma unroll
    for (int o = 32; o > 0; o >>= 1) {
        v.x = min(v.x, __shfl_down(v.x, o, 64));
        v.y = max(v.y, __shfl_down(v.y, o, 64));
        v.z = min(v.z, __shfl_down(v.z, o, 64));
        v.w = max(v.w, __shfl_down(v.w, o, 64));
    }
    return v;
}

__device__ __forceinline__ float4 blockReduceSum4(float4 v, float4* lds4) {
    __syncthreads();
    v = waveReduceSum4(v);
    int lane = threadIdx.x & 63, wave = threadIdx.x >> 6;
    if (lane == 0) lds4[wave] = v;
    __syncthreads();
    int nw = blockDim.x >> 6;
    float4 r = (threadIdx.x < nw) ? lds4[threadIdx.x] : make_float4(0.f, 0.f, 0.f, 0.f);
    if (threadIdx.x < 64) r = waveReduceSum4(r);
    if (threadIdx.x == 0) lds4[0] = r;
    __syncthreads();
    return lds4[0];
}

#define COARSE_SENT (1 << 29)

__device__ __forceinline__ int4 blockReduceBounds(int4 v, int4* ldsi4) {
    __syncthreads();
    v = waveReduceBounds(v);
    int lane = threadIdx.x & 63, wave = threadIdx.x >> 6;
    if (lane == 0) ldsi4[wave] = v;
    __syncthreads();
    int nw = blockDim.x >> 6;
    int4 r = (threadIdx.x < nw) ? ldsi4[threadIdx.x]
                                : make_int4(COARSE_SENT, -1, COARSE_SENT, -1);
    if (threadIdx.x < 64) r = waveReduceBounds(r);
    if (threadIdx.x == 0) ldsi4[0] = r;
    __syncthreads();
    return ldsi4[0];
}

// ---------------- per-float4 body ----------------
// Single-atan2 phase diff: dph = w + 2pi*sigma, w = atan2(cross, dot).
// sigma=+1 iff (phi_p>0 & phi_l<=0 & w<0); sigma=-1 iff (phi_p<=0 & phi_l>0 & w>0).
// Exactly reproduces atan2(pi,pr)-atan2(li,lr); verified absmax 0.0 in R5.
__device__ __forceinline__ void process4(float4 lrv, float4 liv, float4 prv, float4 piv,
                                         int v,
                                         float4& sums,      // x:r y:i z:int w:ph
                                         int4& bounds) {    // x:cfr4 y:clr4 z:cfi4 w:cli4
#pragma unroll
    for (int k = 0; k < 4; ++k) {
        float lrk = (&lrv.x)[k], lik = (&liv.x)[k];
        float prk = (&prv.x)[k], pik = (&piv.x)[k];

        float dr = prk - lrk;  sums.x = fmaf(dr, dr, sums.x);
        float di = pik - lik;  sums.y = fmaf(di, di, sums.y);

        float lint = fmaf(lrk, lrk, lik * lik);
        float pint = fmaf(prk, prk, pik * pik);
        float dint = pint - lint;  sums.z = fmaf(dint, dint, sums.z);

        float cross = fmaf(pik, lrk, -(prk * lik));   // pi*lr - pr*li
        float dotv  = fmaf(prk, lrk,   pik * lik);    // pr*lr + pi*li
        float w = fast_atan2f(cross, dotv);
        bool php = pik > 0.0f;
        bool phl = lik > 0.0f;
        float sigma = (php && !phl && w < 0.0f) ?  1.0f
                    : ((!php && phl && w > 0.0f) ? -1.0f : 0.0f);
        float dph = fmaf(sigma, TWO_PI_F, w);
        sums.w += (lint >= PHASE_INT_THR) ? dph * dph : 0.0f;
    }
    // coarse significance per float4 (abs folds into v_max_f32 modifiers)
    float amr = fmaxf(fmaxf(fabsf(lrv.x), fabsf(lrv.y)), fmaxf(fabsf(lrv.z), fabsf(lrv.w)));
    float ami = fmaxf(fmaxf(fabsf(liv.x), fabsf(liv.y)), fmaxf(fabsf(liv.z), fabsf(liv.w)));
    bool sr = amr > SIG_THRESHOLD;
    bool si = ami > SIG_THRESHOLD;
    bounds.x = min(bounds.x, sr ? v : COARSE_SENT);
    bounds.y = sr ? v : bounds.y;          // v monotone increasing per thread
    bounds.z = min(bounds.z, si ? v : COARSE_SENT);
    bounds.w = si ? v : bounds.w;
}

// ---------------- main per-row kernel ----------------
__global__ void __launch_bounds__(512)
prl_row_kernel(const float* __restrict__ pred, const float* __restrict__ label,
               float* __restrict__ row_out, int n, int two_n) {
    __shared__ float4 s_f4[8];
    __shared__ int4 s_i4[8];
    __shared__ int s_b[4];

    const int row = blockIdx.x;
    const float* __restrict__ P = pred  + (size_t)row * two_n;
    const float* __restrict__ L = label + (size_t)row * two_n;
    const int tid = threadIdx.x;
    const int nt  = blockDim.x;

    const float4* __restrict__ Lr4 = reinterpret_cast<const float4*>(L);
    const float4* __restrict__ Li4 = reinterpret_cast<const float4*>(L + n);
    const float4* __restrict__ Pr4 = reinterpret_cast<const float4*>(P);
    const float4* __restrict__ Pi4 = reinterpret_cast<const float4*>(P + n);

    float4 sums = make_float4(0.f, 0.f, 0.f, 0.f);
    int4 bounds = make_int4(COARSE_SENT, -1, COARSE_SENT, -1);

    const int nvec = n / 4;                  // 8192 float4s per half-row
    for (int v = tid; v < nvec; v += nt) {
        float4 a = Lr4[v], b = Li4[v], c = Pr4[v], d = Pi4[v];
        process4(a, b, c, d, v, sums, bounds);
    }

    float4 tot = blockReduceSum4(sums, s_f4);
    int4 b4 = blockReduceBounds(bounds, s_i4);

    // refine coarse (float4-granularity) bounds to exact element bounds
    if (tid < 4) s_b[tid] = (tid & 1) ? -1 : n;
    __syncthreads();
    if (tid < 16) {
        int which = tid >> 2;                     // 0:fr 1:lr 2:fi 3:li
        int k = tid & 3;
        const float* base = (which >= 2) ? (L + n) : L;
        int v4 = (which == 0) ? b4.x : (which == 1) ? b4.y : (which == 2) ? b4.z : b4.w;
        bool valid = (which & 1) ? (v4 >= 0) : (v4 < COARSE_SENT);
        if (valid) {
            int idx = v4 * 4 + k;
            if (fabsf(base[idx]) > SIG_THRESHOLD) {
                if (which & 1) atomicMax(&s_b[which], idx);
                else           atomicMin(&s_b[which], idx);
            }
        }
    }
    __syncthreads();
    int fr = s_b[0], lr = s_b[1], fi = s_b[2], li = s_b[3];
    if (fr == n) { fr = 0; lr = n - 1; }   // no significant element: scale 1 everywhere
    if (fi == n) { fi = 0; li = n - 1; }

    // extra 1x contribution for the two outside spans (usually ~empty)
    float4 osum = make_float4(0.f, 0.f, 0.f, 0.f);   // x: o_r, y: o_i
    for (int i = tid; i < fr; i += nt)          { float d = P[i] - L[i];         osum.x = fmaf(d, d, osum.x); }
    for (int i = lr + 1 + tid; i < n; i += nt)  { float d = P[i] - L[i];         osum.x = fmaf(d, d, osum.x); }
    for (int i = tid; i < fi; i += nt)          { float d = P[n + i] - L[n + i]; osum.y = fmaf(d, d, osum.y); }
    for (int i = li + 1 + tid; i < n; i += nt)  { float d = P[n + i] - L[n + i]; osum.y = fmaf(d, d, osum.y); }

    float4 otot = blockReduceSum4(osum, s_f4);

    if (tid == 0) {
        float wr = tot.x + otot.x;
        float wi = tot.y + otot.y;
        row_out[row] = (wr + wi + 10.0f * tot.z + 5.0f * tot.w) / (float)n;
    }
}

// ---------------- finalize: mean over rows ----------------
__global__ void __launch_bounds__(1024)
prl_finalize_kernel(const float* __restrict__ rows, float* __restrict__ out, int B) {
    __shared__ float4 s_f4[16];
    float4 v = make_float4(0.f, 0.f, 0.f, 0.f);
    for (int i = threadIdx.x; i < B; i += blockDim.x) v.x += rows[i];
    __syncthreads();
    v = waveReduceSum4(v);
    int lane = threadIdx.x & 63, wave = threadIdx.x >> 6;
    if (lane == 0) s_f4[wave] = v;
    __syncthreads();
    int nw = blockDim.x >> 6;
    float4 r = (threadIdx.x < nw) ? s_f4[threadIdx.x] : make_float4(0.f, 0.f, 0.f, 0.f);
    if (threadIdx.x < 64) r = waveReduceSum4(r);
    if (threadIdx.x == 0) out[0] = r.x / (float)B;
}

extern "C" void kernel_launch(void* const* d_in, const int* in_sizes, int n_in,
                              void* d_out, int out_size, void* d_ws, size_t ws_size,
                              hipStream_t stream) {
    const float* pred  = (const float*)d_in[0];
    const float* label = (const float*)d_in[1];
    // spectrogram (d_in[2]) is unused by the reference.

    const int B     = in_sizes[2] / (128 * 128);   // 1024
    const int two_n = in_sizes[0] / B;             // 65536
    const int n     = two_n / 2;                   // 32768

    float* row_out = (float*)d_ws;                 // B floats of scratch
    float* out     = (float*)d_out;

    prl_row_kernel<<<B, 512, 0, stream>>>(pred, label, row_out, n, two_n);
    prl_finalize_kernel<<<1, 1024, 0, stream>>>(row_out, out, B);
}